// Round 9
// baseline (297.395 us; speedup 1.0000x reference)
//
#include <hip/hip_runtime.h>
#include <hip/hip_bf16.h>

// Problem constants
#define BB     16
#define NBLK   4096
#define HD     128
#define NE     65536
#define MTOT   (BB * NBLK)          // 65536 rows

typedef __attribute__((ext_vector_type(8))) short bf16x8;   // MFMA A/B frag (4 VGPRs)
typedef __attribute__((ext_vector_type(4))) float f32x4;    // MFMA C/D frag

__device__ __forceinline__ float bf2f(unsigned short u) {
    union { unsigned int i; float f; } v; v.i = ((unsigned int)u) << 16; return v.f;
}
// bit-math RNE f2bf (R7-proven; R8's __bf16 cast was confounded with the
// mega regression -> reverted)
__device__ __forceinline__ unsigned short f2bf(float f) {
    union { float f; unsigned int i; } v; v.f = f;
    unsigned int u = v.i;
    unsigned int r = u + 0x7FFFu + ((u >> 16) & 1u);   // RNE
    return (unsigned short)(r >> 16);
}
__device__ __forceinline__ float ldf(const void* p, size_t i, int f32m) {
    return f32m ? ((const float*)p)[i] : bf2f(((const unsigned short*)p)[i]);
}
// block_active accessor: mode 0=int32, 1=int8/bool, 2=bf16, 3=f32
__device__ __forceinline__ int get_active(const void* p, int i, int mode) {
    switch (mode) {
        case 1:  return ((const unsigned char*)p)[i] != 0;
        case 2:  return ((const unsigned short*)p)[i] != 0;
        case 3:  return ((const float*)p)[i] != 0.f;
        default: return ((const int*)p)[i] != 0;
    }
}
// fast ELU / sigmoid: v_exp_f32 path (~2 ulp; irrelevant vs bf16 rounding)
__device__ __forceinline__ float elu_f(float v) {
    const float e = __expf(v);
    return v > 0.f ? v : e - 1.f;
}
__device__ __forceinline__ float sig_f(float v) {
    return 1.f / (1.f + __expf(-v));
}

// ---------------------------------------------------------------------------
// Dtype probe (wave-parallel). flags[0]=floats-are-f32, flags[1]=active mode.
// ---------------------------------------------------------------------------
__global__ void probe_k(const unsigned int* __restrict__ es,
                        const unsigned int* __restrict__ act,
                        int* __restrict__ flags)
{
    const int lane = threadIdx.x;          // 64 threads, 1 wave
    const unsigned int v0 = act[lane], v1 = act[64 + lane];
    auto le1  = [](unsigned int v) { return v <= 1u; };
    auto byt  = [](unsigned int v) {
        return ((v & 0xFFu) <= 1u) && (((v >> 8) & 0xFFu) <= 1u) &&
               (((v >> 16) & 0xFFu) <= 1u) && ((v >> 24) <= 1u); };
    auto f32b = [](unsigned int v) { return v == 0u || v == 0x3F800000u; };
    auto bfb  = [](unsigned int v) {
        unsigned short h0 = (unsigned short)(v & 0xFFFFu), h1 = (unsigned short)(v >> 16);
        return (h0 == 0u || h0 == 0x3F80u) && (h1 == 0u || h1 == 0x3F80u); };
    const unsigned long long m_le1 = __ballot(le1(v0) && le1(v1));
    const unsigned long long m_byt = __ballot(byt(v0) && byt(v1));
    const unsigned long long m_f32 = __ballot(f32b(v0) && f32b(v1));
    const unsigned long long m_bf  = __ballot(bfb(v0) && bfb(v1));
    if (lane == 0) {
        flags[0] = (es[0] != 0x3F003F00u) ? 1 : 0;
        const unsigned long long full = ~0ull;
        flags[1] = (m_le1 == full) ? 0
                 : (m_byt == full) ? 1
                 : (m_f32 == full) ? 3
                 : (m_bf  == full) ? 2 : 0;
    }
}

// ---------------------------------------------------------------------------
// Transpose the 6 weight matrices (K x N row-major) into WT (N x K, bf16).
// ---------------------------------------------------------------------------
__global__ __launch_bounds__(256) void transpose_k(
    const void* p0, const void* p1, const void* p2, const void* p3,
    const void* p4, const void* p5, unsigned short* __restrict__ wsT,
    const int* __restrict__ flags)
{
    const void* srcs[6]  = {p0, p1, p2, p3, p4, p5};
    const int eoffs[6]   = {0, 0, 0, 32768, 0, 32768};
    const int Ks[6]      = {128, 256, 128, 128, 256, 256};
    const int nsh[6]     = {7,   7,   8,   8,   7,   7};
    const int offs[6]    = {0, 16384, 49152, 81920, 114688, 147456};
    const int f32m = flags[0];
    const int z = blockIdx.y;
    const int K = Ks[z];
    const int Nn = 1 << nsh[z];
    const int idx = blockIdx.x * 256 + threadIdx.x;
    if (idx >= K * Nn) return;
    const int k = idx >> nsh[z];
    const int n = idx & (Nn - 1);
    wsT[offs[z] + n * K + k] = f2bf(ldf(srcs[z], (size_t)eoffs[z] + idx, f32m));
}

// ---------------------------------------------------------------------------
// CSR build: edges grouped by dst. count -> scan -> fill (records slot of e).
// ---------------------------------------------------------------------------
__global__ __launch_bounds__(256) void csr_count_k(const int* __restrict__ edst,
                                                   int* __restrict__ cnt)
{
    const int e = blockIdx.x * 256 + threadIdx.x;
    atomicAdd(&cnt[edst[e]], 1);
}

__global__ __launch_bounds__(1024) void csr_scan_k(const int* __restrict__ cnt,
                                                   int* __restrict__ ofs,
                                                   int* __restrict__ cur)
{
    __shared__ int part[1024];
    const int t = threadIdx.x;
    const int4 c = ((const int4*)cnt)[t];
    part[t] = c.x + c.y + c.z + c.w;
    __syncthreads();
    #pragma unroll
    for (int off = 1; off < 1024; off <<= 1) {
        const int v = (t >= off) ? part[t - off] : 0;
        __syncthreads();
        part[t] += v;
        __syncthreads();
    }
    const int base = t ? part[t - 1] : 0;
    int4 o;
    o.x = base; o.y = o.x + c.x; o.z = o.y + c.y; o.w = o.z + c.z;
    ((int4*)ofs)[t] = o;
    ((int4*)cur)[t] = o;
    if (t == 1023) ofs[4096] = part[1023];
}

__global__ __launch_bounds__(256) void csr_fill_k(const int* __restrict__ edst,
                                                  int* __restrict__ cur,
                                                  int* __restrict__ eidx,
                                                  int* __restrict__ pos_e)
{
    const int e = blockIdx.x * 256 + threadIdx.x;
    const int pos = atomicAdd(&cur[edst[e]], 1);
    eidx[pos] = e;
    pos_e[e] = pos;
}

// ---------------------------------------------------------------------------
// edge_w[b,e] (f32, output) + compact[b][slot] = (w, src) for gather.
// ---------------------------------------------------------------------------
__global__ __launch_bounds__(256) void edge_k(
    const void* __restrict__ es, const void* __restrict__ ctE,
    const int* __restrict__ ctype, const int* __restrict__ esrc, const int* __restrict__ edst,
    const void* __restrict__ act, const int* __restrict__ pos_e,
    float* __restrict__ out_ew, float2* __restrict__ compact,
    const int* __restrict__ flags)
{
    const int f32m = flags[0], am = flags[1];
    const int idx = blockIdx.x * 256 + threadIdx.x;    // [0, B*E)
    const int b = idx >> 16;
    const int e = idx & 65535;
    const int s = esrc[e];
    const float sv  = sig_f(ldf(es, e, f32m));
    const float emb = ldf(ctE, (size_t)ctype[b] * NE + e, f32m);
    const int a1 = get_active(act, b * NBLK + s, am);
    const int a2 = get_active(act, b * NBLK + edst[e], am);
    const float w = (a1 && a2) ? sv * emb : 0.f;
    out_ew[idx] = w;
    compact[((size_t)b << 16) + pos_e[e]] = make_float2(w, __int_as_float(s));
}

// ---------------------------------------------------------------------------
// Dst-centric message reduction. One wave per (b,d); 4 edge-subgroups x 16
// h-slots. XCD-aware swizzle.
// ---------------------------------------------------------------------------
__global__ __launch_bounds__(256) void gather_k(
    const float2* __restrict__ compact, const int* __restrict__ ofs,
    const unsigned short* __restrict__ hr, unsigned short* __restrict__ msg)
{
    const int blk = blockIdx.x;                 // 16384 blocks
    const int xcd = blk & 7;
    const int i   = blk >> 3;                   // 0..2047
    const int b   = xcd * 2 + (i & 1);
    const int d   = ((i >> 1) << 2) | (threadIdx.x >> 6);
    const int lane = threadIdx.x & 63;
    const int sub  = lane >> 4;
    const int l15  = lane & 15;
    const int j1 = ofs[d + 1];
    const size_t bbase = (size_t)b * NBLK * HD;
    const float2* cb = compact + ((size_t)b << 16);
    float acc[8];
    #pragma unroll
    for (int i2 = 0; i2 < 8; ++i2) acc[i2] = 0.f;
    int j = ofs[d] + sub;
    float2 c = (j < j1) ? cb[j] : make_float2(0.f, 0.f);
    while (j < j1) {
        const int jn = j + 4;
        const float2 cn = (jn < j1) ? cb[jn] : make_float2(0.f, 0.f);
        if (c.x != 0.f) {
            const int src = __float_as_int(c.y);
            const bf16x8 v = *(const bf16x8*)(hr + bbase + (size_t)src * HD + l15 * 8);
            #pragma unroll
            for (int i2 = 0; i2 < 8; ++i2)
                acc[i2] += c.x * bf2f((unsigned short)v[i2]);
        }
        c = cn; j = jn;
    }
    #pragma unroll
    for (int i2 = 0; i2 < 8; ++i2) {
        acc[i2] += __shfl_xor(acc[i2], 16);
        acc[i2] += __shfl_xor(acc[i2], 32);
    }
    if (sub == 0) {
        bf16x8 o;
        #pragma unroll
        for (int i2 = 0; i2 < 8; ++i2) o[i2] = (short)f2bf(acc[i2]);
        *(bf16x8*)(msg + bbase + (size_t)d * HD + l15 * 8) = o;
    }
}

// ---------------------------------------------------------------------------
// ROUTE kernel (fused cvt + GEMM): KEPT from R8 — the non-mega pipeline
// improved ~30us with this fusion. Per 128-row block:
//   phase A: bt (f32 or bf16) -> bt16, coalesced T=0 burst (warms L2),
//   phase B: hr = elu(bt @ Wp + bp), A-frags loaded straight from bt
//            (f32->bf16 in-register; span is L2-hot from phase A).
// ---------------------------------------------------------------------------
__global__ __launch_bounds__(256) void route_k(
    const void* __restrict__ bt,
    unsigned short* __restrict__ bt16,
    const unsigned short* __restrict__ WT,
    const void* __restrict__ bias,
    unsigned short* __restrict__ hr,
    const int* __restrict__ flags)
{
    constexpr int K = 128, N = 128, KI = 4, NTW = 2, TILES = 8, NBUF = 4;
    const int f32m = flags[0];
    const int t    = threadIdx.x;
    const int lane = t & 63;
    const int wave = t >> 6;
    const int q    = lane >> 4;
    const int l15  = lane & 15;
    const int n0   = wave * 32;

    // ---- phase A: cvt/copy this block's 128x128 span ----
    {
        const size_t base = (size_t)blockIdx.x * (128 * HD);
        #pragma unroll
        for (int it = 0; it < 8; ++it) {
            const size_t i = base + (size_t)it * 2048 + (size_t)t * 8;
            if (f32m) {
                const float* qp = (const float*)bt + i;
                f32x4 lo = *(const f32x4*)qp;
                f32x4 hi = *(const f32x4*)(qp + 4);
                bf16x8 r;
                #pragma unroll
                for (int j = 0; j < 4; ++j) { r[j] = (short)f2bf(lo[j]); r[4 + j] = (short)f2bf(hi[j]); }
                *(bf16x8*)(bt16 + i) = r;
            } else {
                *(bf16x8*)(bt16 + i) = *(const bf16x8*)((const unsigned short*)bt + i);
            }
        }
    }

    // ---- B frags + bias ----
    bf16x8 Bf[KI][NTW];
    #pragma unroll
    for (int ki = 0; ki < KI; ++ki)
        #pragma unroll
        for (int nt = 0; nt < NTW; ++nt)
            Bf[ki][nt] = *(const bf16x8*)(WT + (size_t)(n0 + nt * 16 + l15) * K + ki * 32 + q * 8);
    float biasv[NTW];
    #pragma unroll
    for (int nt = 0; nt < NTW; ++nt)
        biasv[nt] = ldf(bias, n0 + nt * 16 + l15, f32m);

    const int tile0 = blockIdx.x * TILES;
    bf16x8 Af[NBUF][KI];
    auto loadA = [&](int tt) {
        const int arow = (tile0 + tt) * 16 + l15;
        if (f32m) {
            const float* ap = (const float*)bt + (size_t)arow * K;
            #pragma unroll
            for (int ki = 0; ki < KI; ++ki) {
                const int k = ki * 32 + q * 8;
                f32x4 a0 = *(const f32x4*)(ap + k);
                f32x4 a1 = *(const f32x4*)(ap + k + 4);
                bf16x8 r;
                #pragma unroll
                for (int j = 0; j < 4; ++j) { r[j] = (short)f2bf(a0[j]); r[4 + j] = (short)f2bf(a1[j]); }
                Af[tt % NBUF][ki] = r;
            }
        } else {
            const unsigned short* ap = (const unsigned short*)bt + (size_t)arow * K;
            #pragma unroll
            for (int ki = 0; ki < KI; ++ki)
                Af[tt % NBUF][ki] = *(const bf16x8*)(ap + ki * 32 + q * 8);
        }
    };
    #pragma unroll
    for (int p = 0; p < NBUF; ++p) loadA(p);

    #pragma unroll
    for (int tt = 0; tt < TILES; ++tt) {
        const int s = tt % NBUF;
        f32x4 acc[NTW];
        #pragma unroll
        for (int i = 0; i < NTW; ++i) acc[i] = (f32x4){0.f, 0.f, 0.f, 0.f};
        #pragma unroll
        for (int ki = 0; ki < KI; ++ki)
            #pragma unroll
            for (int nt = 0; nt < NTW; ++nt)
                acc[nt] = __builtin_amdgcn_mfma_f32_16x16x32_bf16(Af[s][ki], Bf[ki][nt], acc[nt], 0, 0, 0);

        if (tt + NBUF < TILES) loadA(tt + NBUF);

        const int m0 = (tile0 + tt) * 16;
        #pragma unroll
        for (int nt = 0; nt < NTW; ++nt) {
            #pragma unroll
            for (int r = 0; r < 4; ++r) {
                const int row = m0 + q * 4 + r;
                const int col = n0 + nt * 16 + l15;
                const float v = acc[nt][r] + biasv[nt];
                hr[(size_t)row * N + col] = f2bf(elu_f(v));
            }
        }
    }
}

// ---------------------------------------------------------------------------
// MEGA (R7-measured 103us version, restored verbatim): 128 rows/block,
// 8 waves, grid 512, solo-block design, T=0 epilogue-operand burst.
// R8 post-mortem: hoisting B1 loads ABOVE barrier P1 regressed +31us — the
// compiler's mandatory `s_waitcnt vmcnt(0)` before s_barrier serializes all
// waves at the drain; B1 must load AFTER P1 where LN compute hides it.
// Prefetch only pays when loads drain under COMPUTE, never into a barrier.
// ---------------------------------------------------------------------------
#define XI(xt, row, col)      x_lds[xt][row][((col) + 4 * (row)) & 127]
#define UI(hf, tl, row, col)  U[hf][tl][row][((col) + 8 * (row)) & 255]

__global__ __launch_bounds__(512, 2) void mega_k(
    const unsigned short* __restrict__ bt16,
    const unsigned short* __restrict__ msg,
    const void* __restrict__ btf,             // original bt (f32 or bf16)
    const unsigned short* __restrict__ WT,    // weight table (see launch)
    const void* __restrict__ bg,
    const void* __restrict__ b1, const void* __restrict__ b2,
    const void* __restrict__ lns, const void* __restrict__ lnb,
    float* __restrict__ xout,
    const int* __restrict__ flags)
{
    __shared__ __align__(16) float          x_lds[4][32][128];    // 64 KB
    __shared__ __align__(16) unsigned short U[2][2][32][256];     // 64 KB

    const int f32m = flags[0];
    const int t    = threadIdx.x;
    const int lane = t & 63;
    const int wave = t >> 6;
    const int hf   = wave >> 2;                // half-block: rows [hf*64, hf*64+64)
    const int wv   = wave & 3;                 // role within half (as 4-wave block)
    const int q    = lane >> 4;
    const int l15  = lane & 15;
    const int rhf  = blockIdx.x * 128 + hf * 64;
    const int ng   = wv * 32;

    // ---- T=0 burst: ALL gate-epilogue operands (cold HBM/L3 traffic) ----
    float          btv[2][2][2][4];            // [tl][tt][nt][r]
    unsigned short mgu[2][2][2][4];
    #pragma unroll
    for (int tl = 0; tl < 2; ++tl)
        #pragma unroll
        for (int tt = 0; tt < 2; ++tt)
            #pragma unroll
            for (int nt = 0; nt < 2; ++nt)
                #pragma unroll
                for (int r = 0; r < 4; ++r) {
                    const size_t gi = (size_t)(rhf + tl * 32 + tt * 16 + q * 4 + r) * HD
                                      + ng + nt * 16 + l15;
                    btv[tl][tt][nt][r] = ldf(btf, gi, f32m);
                    mgu[tl][tt][nt][r] = msg[gi];
                }

    // ================= Gate: x = bt + sig([bt,msg]@Wg + bg)*msg =============
    const unsigned short* WgT = WT + 16384;    // (128 N x 256 K)

    bf16x8 Bg[8][2];
    #pragma unroll
    for (int ki = 0; ki < 8; ++ki)
        #pragma unroll
        for (int nt = 0; nt < 2; ++nt)
            Bg[ki][nt] = *(const bf16x8*)(WgT + (size_t)(ng + nt * 16 + l15) * 256 + ki * 32 + q * 8);
    float biasg[2];
    #pragma unroll
    for (int nt = 0; nt < 2; ++nt) biasg[nt] = ldf(bg, ng + nt * 16 + l15, f32m);

    #pragma unroll
    for (int tl = 0; tl < 2; ++tl) {
        const int xt = hf * 2 + tl;
        // A frags for BOTH 16-row tiles up front (16 loads, no VALU between)
        bf16x8 Ag[2][8];
        #pragma unroll
        for (int tt = 0; tt < 2; ++tt) {
            const int arow = rhf + tl * 32 + tt * 16 + l15;
            #pragma unroll
            for (int ki = 0; ki < 8; ++ki) {
                const int k = ki * 32 + q * 8;
                Ag[tt][ki] = (k < HD)
                    ? *(const bf16x8*)(bt16 + (size_t)arow * HD + k)
                    : *(const bf16x8*)(msg  + (size_t)arow * HD + (k - HD));
            }
        }
        #pragma unroll
        for (int tt = 0; tt < 2; ++tt) {
            f32x4 acc[2];
            #pragma unroll
            for (int nt = 0; nt < 2; ++nt) acc[nt] = (f32x4){0.f, 0.f, 0.f, 0.f};
            __builtin_amdgcn_s_setprio(1);
            #pragma unroll
            for (int ki = 0; ki < 8; ++ki)
                #pragma unroll
                for (int nt = 0; nt < 2; ++nt)
                    acc[nt] = __builtin_amdgcn_mfma_f32_16x16x32_bf16(Ag[tt][ki], Bg[ki][nt], acc[nt], 0, 0, 0);
            __builtin_amdgcn_s_setprio(0);
            #pragma unroll
            for (int nt = 0; nt < 2; ++nt)
                #pragma unroll
                for (int r = 0; r < 4; ++r) {
                    const float g = sig_f(acc[nt][r] + biasg[nt]);
                    XI(xt, tt * 16 + q * 4 + r, ng + nt * 16 + l15) =
                        btv[tl][tt][nt][r] + g * bf2f(mgu[tl][tt][nt][r]);
                }
        }
    }
    __syncthreads();                           // P1: x ready

    // ================= 2 transformer layers ================================
    const int rowln = (t & 255) >> 3;          // 8 thr/row within half-block
    const int seg   = t & 7;
    const int n1 = wv * 64;                    // FFN1 col slice
    const int n2 = wv * 32;                    // FFN2 col slice

    #pragma unroll
    for (int l = 0; l < 2; ++l) {
        const unsigned short* W1T = WT + (l ? 81920  : 49152);   // (256 x 128)
        const unsigned short* W2T = WT + (l ? 147456 : 114688);  // (128 x 256)
        const long b1o = l ? 256 : 0, b2o = l ? 128 : 0, lno = l ? 128 : 0;

        // FFN1 weights AFTER P1: L2 loads drain under the LN compute below
        bf16x8 B1[4][4];
        #pragma unroll
        for (int ki = 0; ki < 4; ++ki)
            #pragma unroll
            for (int nt = 0; nt < 4; ++nt)
                B1[ki][nt] = *(const bf16x8*)(W1T + (size_t)(n1 + nt * 16 + l15) * 128 + ki * 32 + q * 8);
        float bias1[4];
        #pragma unroll
        for (int nt = 0; nt < 4; ++nt) bias1[nt] = ldf(b1, b1o + n1 + nt * 16 + l15, f32m);

        // LN scale/bias hoisted once per layer (tile-invariant, seg cols)
        float lsv[16], lbv[16];
        #pragma unroll
        for (int j = 0; j < 4; ++j)
            #pragma unroll
            for (int k = 0; k < 4; ++k) {
                const int col = seg * 16 + j * 4 + k;
                lsv[j * 4 + k] = ldf(lns, lno + col, f32m);
                lbv[j * 4 + k] = ldf(lnb, lno + col, f32m);
            }

        // ---- LN both tiles -> U[hf][tl] ----
        #pragma unroll
        for (int tl = 0; tl < 2; ++tl) {
            const int xt = hf * 2 + tl;
            f32x4 xv[4];
            #pragma unroll
            for (int j = 0; j < 4; ++j)
                xv[j] = *(const f32x4*)&XI(xt, rowln, seg * 16 + j * 4);
            float s = 0.f, ss = 0.f;
            #pragma unroll
            for (int j = 0; j < 4; ++j)
                #pragma unroll
                for (int k = 0; k < 4; ++k) { const float v = xv[j][k]; s += v; ss += v * v; }
            #pragma unroll
            for (int off = 1; off < 8; off <<= 1) { s += __shfl_xor(s, off); ss += __shfl_xor(ss, off); }
            const float mu = s * (1.f / 128.f);
            const float rs = rsqrtf(ss * (1.f / 128.f) - mu * mu + 1e-5f);
            bf16x8 nv[2];
            #pragma unroll
            for (int j = 0; j < 4; ++j)
                #pragma unroll
                for (int k = 0; k < 4; ++k) {
                    const float nn = (xv[j][k] - mu) * rs * lsv[j * 4 + k] + lbv[j * 4 + k];
                    nv[j >> 1][(j & 1) * 4 + k] = (short)f2bf(nn);
                }
            // cols seg*16 and seg*16+8 are 8-aligned: single swizzled b128/b64 ok
            *(bf16x8*)&UI(hf, tl, rowln, seg * 16)     = nv[0];
            *(bf16x8*)&UI(hf, tl, rowln, seg * 16 + 8) = nv[1];
        }
        __syncthreads();                       // P2: nrm ready

        // ---- FFN1 A-frags for BOTH tiles (then U writable as h) ----
        bf16x8 An[2][2][4];
        #pragma unroll
        for (int tl = 0; tl < 2; ++tl)
            #pragma unroll
            for (int tt = 0; tt < 2; ++tt)
                #pragma unroll
                for (int ki = 0; ki < 4; ++ki)
                    An[tl][tt][ki] = *(const bf16x8*)&UI(hf, tl, tt * 16 + l15, ki * 32 + q * 8);
        __syncthreads();                       // P3: nrm reads done

        // ---- FFN1: h = elu(nrm @ W1 + b1) -> U[hf][tl] ----
        #pragma unroll
        for (int tl = 0; tl < 2; ++tl)
            #pragma unroll
            for (int tt = 0; tt < 2; ++tt) {
                f32x4 acc[4];
                #pragma unroll
                for (int nt = 0; nt < 4; ++nt) acc[nt] = (f32x4){0.f, 0.f, 0.f, 0.f};
                __builtin_amdgcn_s_setprio(1);
                #pragma unroll
                for (int ki = 0; ki < 4; ++ki)
                    #pragma unroll
                    for (int nt = 0; nt < 4; ++nt)
                        acc[nt] = __builtin_amdgcn_mfma_f32_16x16x32_bf16(An[tl][tt][ki], B1[ki][nt], acc[nt], 0, 0, 0);
                __builtin_amdgcn_s_setprio(0);
                #pragma unroll
                for (int nt = 0; nt < 4; ++nt)
                    #pragma unroll
                    for (int r = 0; r < 4; ++r)
                        UI(hf, tl, tt * 16 + q * 4 + r, n1 + nt * 16 + l15) =
                            f2bf(elu_f(acc[nt][r] + bias1[nt]));
            }

        // FFN2 weights (B1 now dead -> never co-live; drains under FFN1 tail)
        bf16x8 B2[8][2];
        #pragma unroll
        for (int ki = 0; ki < 8; ++ki)
            #pragma unroll
            for (int nt = 0; nt < 2; ++nt)
                B2[ki][nt] = *(const bf16x8*)(W2T + (size_t)(n2 + nt * 16 + l15) * 256 + ki * 32 + q * 8);
        float bias2[2];
        #pragma unroll
        for (int nt = 0; nt < 2; ++nt) bias2[nt] = ldf(b2, b2o + n2 + nt * 16 + l15, f32m);
        __syncthreads();                       // P4: h ready

        // ---- FFN2: x += h @ W2 + b2 ----
        #pragma unroll
        for (int tl = 0; tl < 2; ++tl) {
            const int xt = hf * 2 + tl;
            #pragma unroll
            for (int tt = 0; tt < 2; ++tt) {
                bf16x8 Ah[8];
                #pragma unroll
                for (int ki = 0; ki < 8; ++ki)
                    Ah[ki] = *(const bf16x8*)&UI(hf, tl, tt * 16 + l15, ki * 32 + q * 8);
                f32x4 acc[2];
                #pragma unroll
                for (int nt = 0; nt < 2; ++nt) acc[nt] = (f32x4){0.f, 0.f, 0.f, 0.f};
                __builtin_amdgcn_s_setprio(1);
                #pragma unroll
                for (int ki = 0; ki < 8; ++ki)
                    #pragma unroll
                    for (int nt = 0; nt < 2; ++nt)
                        acc[nt] = __builtin_amdgcn_mfma_f32_16x16x32_bf16(Ah[ki], B2[ki][nt], acc[nt], 0, 0, 0);
                __builtin_amdgcn_s_setprio(0);
                #pragma unroll
                for (int nt = 0; nt < 2; ++nt)
                    #pragma unroll
                    for (int r = 0; r < 4; ++r)
                        XI(xt, tt * 16 + q * 4 + r, n2 + nt * 16 + l15) += acc[nt][r] + bias2[nt];
            }
        }
        __syncthreads();                       // P5: x updated, U reads done
    }

    // ================= store: coalesced f32x4, swizzle-aware ===============
    #pragma unroll
    for (int xt = 0; xt < 4; ++xt) {
        float* xo = xout + (size_t)(blockIdx.x * 128 + xt * 32) * HD;
        #pragma unroll
        for (int j = 0; j < 2; ++j) {
            const int idx = j * 512 + t;       // f32x4 index within 32x128 tile
            const int r2  = idx >> 5;
            const int c4  = (idx & 31) * 4;
            *(f32x4*)(xo + (size_t)idx * 4) = *(const f32x4*)&XI(xt, r2, c4);
        }
    }
}

// ---------------------------------------------------------------------------
extern "C" void kernel_launch(void* const* d_in, const int* in_sizes, int n_in,
                              void* d_out, int out_size, void* d_ws, size_t ws_size,
                              hipStream_t stream)
{
    (void)in_sizes; (void)n_in; (void)out_size; (void)ws_size;

    const void* bt  = d_in[0];   // (B,NB,H)
    const void* es  = d_in[1];   // (E,)
    const void* ctE = d_in[2];   // (NCT,E)
    const void* Wp  = d_in[3];   // (H,H)
    const void* bp  = d_in[4];   // (H,)
    const void* Wg  = d_in[5];   // (2H,H)
    const void* bg  = d_in[6];   // (H,)
    const void* lns = d_in[7];   // (NL,H)
    const void* lnb = d_in[8];   // (NL,H)
    const void* W1  = d_in[9];   // (NL,H,2H)
    const void* b1  = d_in[10];  // (NL,2H)
    const void* W2  = d_in[11];  // (NL,2H,H)
    const void* b2  = d_in[12];  // (NL,H)
    const int* ctype = (const int*)d_in[13];
    const int* esrc  = (const int*)d_in[14];
    const int* edst  = (const int*)d_in[15];
    const void* act  = d_in[16]; // (B,NB)

    // Outputs f32, concatenated: x (M*HD) then edge_w (B*E). x lives in d_out.
    float* out_x  = (float*)d_out;
    float* out_ew = out_x + (size_t)MTOT * HD;
    float* x = out_x;

    // Workspace:
    //   [0,1K)              flags
    //   [1K,+16MB)          msg bf16
    //   [1K+16MB,+32MB)     bt16 bf16
    //   [1K+32MB,+48MB)     hr bf16
    //   base48 = 1K+48MB:
    //     cnt @+0 (16K) | ofs @+16K (20K) | cur @+36K (16K)
    //     eidx @+52K (256K) | pos_e @+308K (256K) | WT @+576K (352K)
    //     compact @+1M (8MB)
    char* ws = (char*)d_ws;
    int*            flags = (int*)ws;
    unsigned short* msg   = (unsigned short*)(ws + 1024);
    unsigned short* bt16  = (unsigned short*)(ws + 1024 + (16ull << 20));
    unsigned short* hr    = (unsigned short*)(ws + 1024 + (32ull << 20));
    char* base48 = ws + 1024 + (48ull << 20);
    int*            cnt     = (int*)(base48);
    int*            ofs     = (int*)(base48 + (16 << 10));
    int*            cur     = (int*)(base48 + (36 << 10));
    int*            eidx    = (int*)(base48 + (52 << 10));
    int*            pos_e   = (int*)(base48 + (308 << 10));
    unsigned short* WT      = (unsigned short*)(base48 + (576 << 10));
    float2*         compact = (float2*)(base48 + (1 << 20));

    const int M = MTOT;

    probe_k<<<1, 64, 0, stream>>>((const unsigned int*)es, (const unsigned int*)act, flags);
    hipMemsetAsync(cnt, 0, NBLK * sizeof(int), stream);

    transpose_k<<<dim3(128, 6), 256, 0, stream>>>(Wp, Wg, W1, W1, W2, W2, WT, flags);

    // fused cvt + route GEMM: bt -> bt16, hr = elu(bt @ Wp + bp)
    route_k<<<dim3(M / 128), 256, 0, stream>>>(bt, bt16, WT + 0, bp, hr, flags);

    csr_count_k<<<dim3(NE / 256), 256, 0, stream>>>(edst, cnt);
    csr_scan_k<<<dim3(1), 1024, 0, stream>>>(cnt, ofs, cur);
    csr_fill_k<<<dim3(NE / 256), 256, 0, stream>>>(edst, cur, eidx, pos_e);

    edge_k<<<dim3((BB * NE) / 256), 256, 0, stream>>>(
        es, ctE, ctype, esrc, edst, act, pos_e, out_ew, compact, flags);

    // messages via dst-centric segmented reduction -> bf16
    gather_k<<<dim3(M / 4), 256, 0, stream>>>(compact, ofs, hr, msg);

    // gate + both transformer layers fused; 128 rows/block, 8 waves, grid 512
    mega_k<<<dim3(M / 128), 512, 0, stream>>>(
        bt16, msg, bt, WT, bg, b1, b2, lns, lnb, x, flags);
}

// Round 12
// 293.744 us; speedup vs baseline: 1.0124x; 1.0124x over previous
//
#include <hip/hip_runtime.h>
#include <hip/hip_bf16.h>

// Problem constants
#define BB     16
#define NBLK   4096
#define HD     128
#define NE     65536
#define MTOT   (BB * NBLK)          // 65536 rows

typedef __attribute__((ext_vector_type(8))) short bf16x8;   // MFMA A/B frag (4 VGPRs)
typedef __attribute__((ext_vector_type(4))) float f32x4;    // MFMA C/D frag

__device__ __forceinline__ float bf2f(unsigned short u) {
    union { unsigned int i; float f; } v; v.i = ((unsigned int)u) << 16; return v.f;
}
// HW bf16 convert (RNE scalar cast -> v_cvt; 1 op vs 4-op bit math).
// R8/R9 A/B: non-mega pipeline 162 vs 194us with ONLY this variable changed
// (route_k's f32 path has ~80 critical-path converts/thread). mega's R8
// regression was the B1-hoist, not this (VALU-cycle arithmetic constant).
__device__ __forceinline__ unsigned short f2bf(float f) {
    __bf16 h = (__bf16)f;
    unsigned short u;
    __builtin_memcpy(&u, &h, 2);
    return u;
}
__device__ __forceinline__ float ldf(const void* p, size_t i, int f32m) {
    return f32m ? ((const float*)p)[i] : bf2f(((const unsigned short*)p)[i]);
}
// block_active accessor: mode 0=int32, 1=int8/bool, 2=bf16, 3=f32
__device__ __forceinline__ int get_active(const void* p, int i, int mode) {
    switch (mode) {
        case 1:  return ((const unsigned char*)p)[i] != 0;
        case 2:  return ((const unsigned short*)p)[i] != 0;
        case 3:  return ((const float*)p)[i] != 0.f;
        default: return ((const int*)p)[i] != 0;
    }
}
// fast ELU / sigmoid: v_exp_f32 path (~2 ulp; irrelevant vs bf16 rounding)
__device__ __forceinline__ float elu_f(float v) {
    const float e = __expf(v);
    return v > 0.f ? v : e - 1.f;
}
__device__ __forceinline__ float sig_f(float v) {
    return 1.f / (1.f + __expf(-v));
}

// ---------------------------------------------------------------------------
// Dtype probe (wave-parallel). flags[0]=floats-are-f32, flags[1]=active mode.
// ---------------------------------------------------------------------------
__global__ void probe_k(const unsigned int* __restrict__ es,
                        const unsigned int* __restrict__ act,
                        int* __restrict__ flags)
{
    const int lane = threadIdx.x;          // 64 threads, 1 wave
    const unsigned int v0 = act[lane], v1 = act[64 + lane];
    auto le1  = [](unsigned int v) { return v <= 1u; };
    auto byt  = [](unsigned int v) {
        return ((v & 0xFFu) <= 1u) && (((v >> 8) & 0xFFu) <= 1u) &&
               (((v >> 16) & 0xFFu) <= 1u) && ((v >> 24) <= 1u); };
    auto f32b = [](unsigned int v) { return v == 0u || v == 0x3F800000u; };
    auto bfb  = [](unsigned int v) {
        unsigned short h0 = (unsigned short)(v & 0xFFFFu), h1 = (unsigned short)(v >> 16);
        return (h0 == 0u || h0 == 0x3F80u) && (h1 == 0u || h1 == 0x3F80u); };
    const unsigned long long m_le1 = __ballot(le1(v0) && le1(v1));
    const unsigned long long m_byt = __ballot(byt(v0) && byt(v1));
    const unsigned long long m_f32 = __ballot(f32b(v0) && f32b(v1));
    const unsigned long long m_bf  = __ballot(bfb(v0) && bfb(v1));
    if (lane == 0) {
        flags[0] = (es[0] != 0x3F003F00u) ? 1 : 0;
        const unsigned long long full = ~0ull;
        flags[1] = (m_le1 == full) ? 0
                 : (m_byt == full) ? 1
                 : (m_f32 == full) ? 3
                 : (m_bf  == full) ? 2 : 0;
    }
}

// ---------------------------------------------------------------------------
// Transpose the 6 weight matrices (K x N row-major) into WT (N x K, bf16).
// ---------------------------------------------------------------------------
__global__ __launch_bounds__(256) void transpose_k(
    const void* p0, const void* p1, const void* p2, const void* p3,
    const void* p4, const void* p5, unsigned short* __restrict__ wsT,
    const int* __restrict__ flags)
{
    const void* srcs[6]  = {p0, p1, p2, p3, p4, p5};
    const int eoffs[6]   = {0, 0, 0, 32768, 0, 32768};
    const int Ks[6]      = {128, 256, 128, 128, 256, 256};
    const int nsh[6]     = {7,   7,   8,   8,   7,   7};
    const int offs[6]    = {0, 16384, 49152, 81920, 114688, 147456};
    const int f32m = flags[0];
    const int z = blockIdx.y;
    const int K = Ks[z];
    const int Nn = 1 << nsh[z];
    const int idx = blockIdx.x * 256 + threadIdx.x;
    if (idx >= K * Nn) return;
    const int k = idx >> nsh[z];
    const int n = idx & (Nn - 1);
    wsT[offs[z] + n * K + k] = f2bf(ldf(srcs[z], (size_t)eoffs[z] + idx, f32m));
}

// ---------------------------------------------------------------------------
// CSR build: edges grouped by dst. count -> scan -> fill (records slot of e).
// ---------------------------------------------------------------------------
__global__ __launch_bounds__(256) void csr_count_k(const int* __restrict__ edst,
                                                   int* __restrict__ cnt)
{
    const int e = blockIdx.x * 256 + threadIdx.x;
    atomicAdd(&cnt[edst[e]], 1);
}

__global__ __launch_bounds__(1024) void csr_scan_k(const int* __restrict__ cnt,
                                                   int* __restrict__ ofs,
                                                   int* __restrict__ cur)
{
    __shared__ int part[1024];
    const int t = threadIdx.x;
    const int4 c = ((const int4*)cnt)[t];
    part[t] = c.x + c.y + c.z + c.w;
    __syncthreads();
    #pragma unroll
    for (int off = 1; off < 1024; off <<= 1) {
        const int v = (t >= off) ? part[t - off] : 0;
        __syncthreads();
        part[t] += v;
        __syncthreads();
    }
    const int base = t ? part[t - 1] : 0;
    int4 o;
    o.x = base; o.y = o.x + c.x; o.z = o.y + c.y; o.w = o.z + c.z;
    ((int4*)ofs)[t] = o;
    ((int4*)cur)[t] = o;
    if (t == 1023) ofs[4096] = part[1023];
}

__global__ __launch_bounds__(256) void csr_fill_k(const int* __restrict__ edst,
                                                  int* __restrict__ cur,
                                                  int* __restrict__ eidx,
                                                  int* __restrict__ pos_e)
{
    const int e = blockIdx.x * 256 + threadIdx.x;
    const int pos = atomicAdd(&cur[edst[e]], 1);
    eidx[pos] = e;
    pos_e[e] = pos;
}

// ---------------------------------------------------------------------------
// edge_w[b,e] (f32, output) + compact[b][slot] = (w, src) for gather.
// ---------------------------------------------------------------------------
__global__ __launch_bounds__(256) void edge_k(
    const void* __restrict__ es, const void* __restrict__ ctE,
    const int* __restrict__ ctype, const int* __restrict__ esrc, const int* __restrict__ edst,
    const void* __restrict__ act, const int* __restrict__ pos_e,
    float* __restrict__ out_ew, float2* __restrict__ compact,
    const int* __restrict__ flags)
{
    const int f32m = flags[0], am = flags[1];
    const int idx = blockIdx.x * 256 + threadIdx.x;    // [0, B*E)
    const int b = idx >> 16;
    const int e = idx & 65535;
    const int s = esrc[e];
    const float sv  = sig_f(ldf(es, e, f32m));
    const float emb = ldf(ctE, (size_t)ctype[b] * NE + e, f32m);
    const int a1 = get_active(act, b * NBLK + s, am);
    const int a2 = get_active(act, b * NBLK + edst[e], am);
    const float w = (a1 && a2) ? sv * emb : 0.f;
    out_ew[idx] = w;
    compact[((size_t)b << 16) + pos_e[e]] = make_float2(w, __int_as_float(s));
}

// ---------------------------------------------------------------------------
// Dst-centric message reduction. One wave per (b,d); 4 edge-subgroups x 16
// h-slots. XCD-aware swizzle.
// ---------------------------------------------------------------------------
__global__ __launch_bounds__(256) void gather_k(
    const float2* __restrict__ compact, const int* __restrict__ ofs,
    const unsigned short* __restrict__ hr, unsigned short* __restrict__ msg)
{
    const int blk = blockIdx.x;                 // 16384 blocks
    const int xcd = blk & 7;
    const int i   = blk >> 3;                   // 0..2047
    const int b   = xcd * 2 + (i & 1);
    const int d   = ((i >> 1) << 2) | (threadIdx.x >> 6);
    const int lane = threadIdx.x & 63;
    const int sub  = lane >> 4;
    const int l15  = lane & 15;
    const int j1 = ofs[d + 1];
    const size_t bbase = (size_t)b * NBLK * HD;
    const float2* cb = compact + ((size_t)b << 16);
    float acc[8];
    #pragma unroll
    for (int i2 = 0; i2 < 8; ++i2) acc[i2] = 0.f;
    int j = ofs[d] + sub;
    float2 c = (j < j1) ? cb[j] : make_float2(0.f, 0.f);
    while (j < j1) {
        const int jn = j + 4;
        const float2 cn = (jn < j1) ? cb[jn] : make_float2(0.f, 0.f);
        if (c.x != 0.f) {
            const int src = __float_as_int(c.y);
            const bf16x8 v = *(const bf16x8*)(hr + bbase + (size_t)src * HD + l15 * 8);
            #pragma unroll
            for (int i2 = 0; i2 < 8; ++i2)
                acc[i2] += c.x * bf2f((unsigned short)v[i2]);
        }
        c = cn; j = jn;
    }
    #pragma unroll
    for (int i2 = 0; i2 < 8; ++i2) {
        acc[i2] += __shfl_xor(acc[i2], 16);
        acc[i2] += __shfl_xor(acc[i2], 32);
    }
    if (sub == 0) {
        bf16x8 o;
        #pragma unroll
        for (int i2 = 0; i2 < 8; ++i2) o[i2] = (short)f2bf(acc[i2]);
        *(bf16x8*)(msg + bbase + (size_t)d * HD + l15 * 8) = o;
    }
}

// ---------------------------------------------------------------------------
// ROUTE kernel (fused cvt + GEMM). Per 128-row block:
//   phase A: bt (f32 or bf16) -> bt16, coalesced T=0 burst (warms L2),
//   phase B: hr = elu(bt @ Wp + bp), A-frags loaded straight from bt
//            (f32->bf16 in-register; span is L2-hot from phase A).
// f32 path does ~80 converts/thread on the critical path -> HW f2bf matters.
// ---------------------------------------------------------------------------
__global__ __launch_bounds__(256) void route_k(
    const void* __restrict__ bt,
    unsigned short* __restrict__ bt16,
    const unsigned short* __restrict__ WT,
    const void* __restrict__ bias,
    unsigned short* __restrict__ hr,
    const int* __restrict__ flags)
{
    constexpr int K = 128, N = 128, KI = 4, NTW = 2, TILES = 8, NBUF = 4;
    const int f32m = flags[0];
    const int t    = threadIdx.x;
    const int lane = t & 63;
    const int wave = t >> 6;
    const int q    = lane >> 4;
    const int l15  = lane & 15;
    const int n0   = wave * 32;

    // ---- phase A: cvt/copy this block's 128x128 span ----
    {
        const size_t base = (size_t)blockIdx.x * (128 * HD);
        #pragma unroll
        for (int it = 0; it < 8; ++it) {
            const size_t i = base + (size_t)it * 2048 + (size_t)t * 8;
            if (f32m) {
                const float* qp = (const float*)bt + i;
                f32x4 lo = *(const f32x4*)qp;
                f32x4 hi = *(const f32x4*)(qp + 4);
                bf16x8 r;
                #pragma unroll
                for (int j = 0; j < 4; ++j) { r[j] = (short)f2bf(lo[j]); r[4 + j] = (short)f2bf(hi[j]); }
                *(bf16x8*)(bt16 + i) = r;
            } else {
                *(bf16x8*)(bt16 + i) = *(const bf16x8*)((const unsigned short*)bt + i);
            }
        }
    }

    // ---- B frags + bias ----
    bf16x8 Bf[KI][NTW];
    #pragma unroll
    for (int ki = 0; ki < KI; ++ki)
        #pragma unroll
        for (int nt = 0; nt < NTW; ++nt)
            Bf[ki][nt] = *(const bf16x8*)(WT + (size_t)(n0 + nt * 16 + l15) * K + ki * 32 + q * 8);
    float biasv[NTW];
    #pragma unroll
    for (int nt = 0; nt < NTW; ++nt)
        biasv[nt] = ldf(bias, n0 + nt * 16 + l15, f32m);

    const int tile0 = blockIdx.x * TILES;
    bf16x8 Af[NBUF][KI];
    auto loadA = [&](int tt) {
        const int arow = (tile0 + tt) * 16 + l15;
        if (f32m) {
            const float* ap = (const float*)bt + (size_t)arow * K;
            #pragma unroll
            for (int ki = 0; ki < KI; ++ki) {
                const int k = ki * 32 + q * 8;
                f32x4 a0 = *(const f32x4*)(ap + k);
                f32x4 a1 = *(const f32x4*)(ap + k + 4);
                bf16x8 r;
                #pragma unroll
                for (int j = 0; j < 4; ++j) { r[j] = (short)f2bf(a0[j]); r[4 + j] = (short)f2bf(a1[j]); }
                Af[tt % NBUF][ki] = r;
            }
        } else {
            const unsigned short* ap = (const unsigned short*)bt + (size_t)arow * K;
            #pragma unroll
            for (int ki = 0; ki < KI; ++ki)
                Af[tt % NBUF][ki] = *(const bf16x8*)(ap + ki * 32 + q * 8);
        }
    };
    #pragma unroll
    for (int p = 0; p < NBUF; ++p) loadA(p);

    #pragma unroll
    for (int tt = 0; tt < TILES; ++tt) {
        const int s = tt % NBUF;
        f32x4 acc[NTW];
        #pragma unroll
        for (int i = 0; i < NTW; ++i) acc[i] = (f32x4){0.f, 0.f, 0.f, 0.f};
        #pragma unroll
        for (int ki = 0; ki < KI; ++ki)
            #pragma unroll
            for (int nt = 0; nt < NTW; ++nt)
                acc[nt] = __builtin_amdgcn_mfma_f32_16x16x32_bf16(Af[s][ki], Bf[ki][nt], acc[nt], 0, 0, 0);

        if (tt + NBUF < TILES) loadA(tt + NBUF);

        const int m0 = (tile0 + tt) * 16;
        #pragma unroll
        for (int nt = 0; nt < NTW; ++nt) {
            #pragma unroll
            for (int r = 0; r < 4; ++r) {
                const int row = m0 + q * 4 + r;
                const int col = n0 + nt * 16 + l15;
                const float v = acc[nt][r] + biasv[nt];
                hr[(size_t)row * N + col] = f2bf(elu_f(v));
            }
        }
    }
}

// ---------------------------------------------------------------------------
// MEGA (R7/R9-measured 103us structure, unchanged): 128 rows/block,
// 8 waves, grid 512, solo-block design, T=0 epilogue-operand burst.
// R8 lesson (kept): NO load hoisting above barriers — the compiler's
// mandatory `s_waitcnt vmcnt(0)` before s_barrier serializes all waves at
// the drain. B1 loads AFTER P1 where LN compute hides them.
// ---------------------------------------------------------------------------
#define XI(xt, row, col)      x_lds[xt][row][((col) + 4 * (row)) & 127]
#define UI(hf, tl, row, col)  U[hf][tl][row][((col) + 8 * (row)) & 255]

__global__ __launch_bounds__(512, 2) void mega_k(
    const unsigned short* __restrict__ bt16,
    const unsigned short* __restrict__ msg,
    const void* __restrict__ btf,             // original bt (f32 or bf16)
    const unsigned short* __restrict__ WT,    // weight table (see launch)
    const void* __restrict__ bg,
    const void* __restrict__ b1, const void* __restrict__ b2,
    const void* __restrict__ lns, const void* __restrict__ lnb,
    float* __restrict__ xout,
    const int* __restrict__ flags)
{
    __shared__ __align__(16) float          x_lds[4][32][128];    // 64 KB
    __shared__ __align__(16) unsigned short U[2][2][32][256];     // 64 KB

    const int f32m = flags[0];
    const int t    = threadIdx.x;
    const int lane = t & 63;
    const int wave = t >> 6;
    const int hf   = wave >> 2;                // half-block: rows [hf*64, hf*64+64)
    const int wv   = wave & 3;                 // role within half (as 4-wave block)
    const int q    = lane >> 4;
    const int l15  = lane & 15;
    const int rhf  = blockIdx.x * 128 + hf * 64;
    const int ng   = wv * 32;

    // ---- T=0 burst: ALL gate-epilogue operands (cold HBM/L3 traffic) ----
    float          btv[2][2][2][4];            // [tl][tt][nt][r]
    unsigned short mgu[2][2][2][4];
    #pragma unroll
    for (int tl = 0; tl < 2; ++tl)
        #pragma unroll
        for (int tt = 0; tt < 2; ++tt)
            #pragma unroll
            for (int nt = 0; nt < 2; ++nt)
                #pragma unroll
                for (int r = 0; r < 4; ++r) {
                    const size_t gi = (size_t)(rhf + tl * 32 + tt * 16 + q * 4 + r) * HD
                                      + ng + nt * 16 + l15;
                    btv[tl][tt][nt][r] = ldf(btf, gi, f32m);
                    mgu[tl][tt][nt][r] = msg[gi];
                }

    // ================= Gate: x = bt + sig([bt,msg]@Wg + bg)*msg =============
    const unsigned short* WgT = WT + 16384;    // (128 N x 256 K)

    bf16x8 Bg[8][2];
    #pragma unroll
    for (int ki = 0; ki < 8; ++ki)
        #pragma unroll
        for (int nt = 0; nt < 2; ++nt)
            Bg[ki][nt] = *(const bf16x8*)(WgT + (size_t)(ng + nt * 16 + l15) * 256 + ki * 32 + q * 8);
    float biasg[2];
    #pragma unroll
    for (int nt = 0; nt < 2; ++nt) biasg[nt] = ldf(bg, ng + nt * 16 + l15, f32m);

    #pragma unroll
    for (int tl = 0; tl < 2; ++tl) {
        const int xt = hf * 2 + tl;
        // A frags for BOTH 16-row tiles up front (16 loads, no VALU between)
        bf16x8 Ag[2][8];
        #pragma unroll
        for (int tt = 0; tt < 2; ++tt) {
            const int arow = rhf + tl * 32 + tt * 16 + l15;
            #pragma unroll
            for (int ki = 0; ki < 8; ++ki) {
                const int k = ki * 32 + q * 8;
                Ag[tt][ki] = (k < HD)
                    ? *(const bf16x8*)(bt16 + (size_t)arow * HD + k)
                    : *(const bf16x8*)(msg  + (size_t)arow * HD + (k - HD));
            }
        }
        #pragma unroll
        for (int tt = 0; tt < 2; ++tt) {
            f32x4 acc[2];
            #pragma unroll
            for (int nt = 0; nt < 2; ++nt) acc[nt] = (f32x4){0.f, 0.f, 0.f, 0.f};
            __builtin_amdgcn_s_setprio(1);
            #pragma unroll
            for (int ki = 0; ki < 8; ++ki)
                #pragma unroll
                for (int nt = 0; nt < 2; ++nt)
                    acc[nt] = __builtin_amdgcn_mfma_f32_16x16x32_bf16(Ag[tt][ki], Bg[ki][nt], acc[nt], 0, 0, 0);
            __builtin_amdgcn_s_setprio(0);
            #pragma unroll
            for (int nt = 0; nt < 2; ++nt)
                #pragma unroll
                for (int r = 0; r < 4; ++r) {
                    const float g = sig_f(acc[nt][r] + biasg[nt]);
                    XI(xt, tt * 16 + q * 4 + r, ng + nt * 16 + l15) =
                        btv[tl][tt][nt][r] + g * bf2f(mgu[tl][tt][nt][r]);
                }
        }
    }
    __syncthreads();                           // P1: x ready

    // ================= 2 transformer layers ================================
    const int rowln = (t & 255) >> 3;          // 8 thr/row within half-block
    const int seg   = t & 7;
    const int n1 = wv * 64;                    // FFN1 col slice
    const int n2 = wv * 32;                    // FFN2 col slice

    #pragma unroll
    for (int l = 0; l < 2; ++l) {
        const unsigned short* W1T = WT + (l ? 81920  : 49152);   // (256 x 128)
        const unsigned short* W2T = WT + (l ? 147456 : 114688);  // (128 x 256)
        const long b1o = l ? 256 : 0, b2o = l ? 128 : 0, lno = l ? 128 : 0;

        // FFN1 weights AFTER P1: L2 loads drain under the LN compute below
        bf16x8 B1[4][4];
        #pragma unroll
        for (int ki = 0; ki < 4; ++ki)
            #pragma unroll
            for (int nt = 0; nt < 4; ++nt)
                B1[ki][nt] = *(const bf16x8*)(W1T + (size_t)(n1 + nt * 16 + l15) * 128 + ki * 32 + q * 8);
        float bias1[4];
        #pragma unroll
        for (int nt = 0; nt < 4; ++nt) bias1[nt] = ldf(b1, b1o + n1 + nt * 16 + l15, f32m);

        // LN scale/bias hoisted once per layer (tile-invariant, seg cols)
        float lsv[16], lbv[16];
        #pragma unroll
        for (int j = 0; j < 4; ++j)
            #pragma unroll
            for (int k = 0; k < 4; ++k) {
                const int col = seg * 16 + j * 4 + k;
                lsv[j * 4 + k] = ldf(lns, lno + col, f32m);
                lbv[j * 4 + k] = ldf(lnb, lno + col, f32m);
            }

        // ---- LN both tiles -> U[hf][tl] ----
        #pragma unroll
        for (int tl = 0; tl < 2; ++tl) {
            const int xt = hf * 2 + tl;
            f32x4 xv[4];
            #pragma unroll
            for (int j = 0; j < 4; ++j)
                xv[j] = *(const f32x4*)&XI(xt, rowln, seg * 16 + j * 4);
            float s = 0.f, ss = 0.f;
            #pragma unroll
            for (int j = 0; j < 4; ++j)
                #pragma unroll
                for (int k = 0; k < 4; ++k) { const float v = xv[j][k]; s += v; ss += v * v; }
            #pragma unroll
            for (int off = 1; off < 8; off <<= 1) { s += __shfl_xor(s, off); ss += __shfl_xor(ss, off); }
            const float mu = s * (1.f / 128.f);
            const float rs = rsqrtf(ss * (1.f / 128.f) - mu * mu + 1e-5f);
            bf16x8 nv[2];
            #pragma unroll
            for (int j = 0; j < 4; ++j)
                #pragma unroll
                for (int k = 0; k < 4; ++k) {
                    const float nn = (xv[j][k] - mu) * rs * lsv[j * 4 + k] + lbv[j * 4 + k];
                    nv[j >> 1][(j & 1) * 4 + k] = (short)f2bf(nn);
                }
            // cols seg*16 and seg*16+8 are 8-aligned: single swizzled b128/b64 ok
            *(bf16x8*)&UI(hf, tl, rowln, seg * 16)     = nv[0];
            *(bf16x8*)&UI(hf, tl, rowln, seg * 16 + 8) = nv[1];
        }
        __syncthreads();                       // P2: nrm ready

        // ---- FFN1 A-frags for BOTH tiles (then U writable as h) ----
        bf16x8 An[2][2][4];
        #pragma unroll
        for (int tl = 0; tl < 2; ++tl)
            #pragma unroll
            for (int tt = 0; tt < 2; ++tt)
                #pragma unroll
                for (int ki = 0; ki < 4; ++ki)
                    An[tl][tt][ki] = *(const bf16x8*)&UI(hf, tl, tt * 16 + l15, ki * 32 + q * 8);
        __syncthreads();                       // P3: nrm reads done

        // ---- FFN1: h = elu(nrm @ W1 + b1) -> U[hf][tl] ----
        #pragma unroll
        for (int tl = 0; tl < 2; ++tl)
            #pragma unroll
            for (int tt = 0; tt < 2; ++tt) {
                f32x4 acc[4];
                #pragma unroll
                for (int nt = 0; nt < 4; ++nt) acc[nt] = (f32x4){0.f, 0.f, 0.f, 0.f};
                __builtin_amdgcn_s_setprio(1);
                #pragma unroll
                for (int ki = 0; ki < 4; ++ki)
                    #pragma unroll
                    for (int nt = 0; nt < 4; ++nt)
                        acc[nt] = __builtin_amdgcn_mfma_f32_16x16x32_bf16(An[tl][tt][ki], B1[ki][nt], acc[nt], 0, 0, 0);
                __builtin_amdgcn_s_setprio(0);
                #pragma unroll
                for (int nt = 0; nt < 4; ++nt)
                    #pragma unroll
                    for (int r = 0; r < 4; ++r)
                        UI(hf, tl, tt * 16 + q * 4 + r, n1 + nt * 16 + l15) =
                            f2bf(elu_f(acc[nt][r] + bias1[nt]));
            }

        // FFN2 weights (B1 now dead -> never co-live; drains under FFN1 tail)
        bf16x8 B2[8][2];
        #pragma unroll
        for (int ki = 0; ki < 8; ++ki)
            #pragma unroll
            for (int nt = 0; nt < 2; ++nt)
                B2[ki][nt] = *(const bf16x8*)(W2T + (size_t)(n2 + nt * 16 + l15) * 256 + ki * 32 + q * 8);
        float bias2[2];
        #pragma unroll
        for (int nt = 0; nt < 2; ++nt) bias2[nt] = ldf(b2, b2o + n2 + nt * 16 + l15, f32m);
        __syncthreads();                       // P4: h ready

        // ---- FFN2: x += h @ W2 + b2 ----
        #pragma unroll
        for (int tl = 0; tl < 2; ++tl) {
            const int xt = hf * 2 + tl;
            #pragma unroll
            for (int tt = 0; tt < 2; ++tt) {
                bf16x8 Ah[8];
                #pragma unroll
                for (int ki = 0; ki < 8; ++ki)
                    Ah[ki] = *(const bf16x8*)&UI(hf, tl, tt * 16 + l15, ki * 32 + q * 8);
                f32x4 acc[2];
                #pragma unroll
                for (int nt = 0; nt < 2; ++nt) acc[nt] = (f32x4){0.f, 0.f, 0.f, 0.f};
                __builtin_amdgcn_s_setprio(1);
                #pragma unroll
                for (int ki = 0; ki < 8; ++ki)
                    #pragma unroll
                    for (int nt = 0; nt < 2; ++nt)
                        acc[nt] = __builtin_amdgcn_mfma_f32_16x16x32_bf16(Ah[ki], B2[ki][nt], acc[nt], 0, 0, 0);
                __builtin_amdgcn_s_setprio(0);
                #pragma unroll
                for (int nt = 0; nt < 2; ++nt)
                    #pragma unroll
                    for (int r = 0; r < 4; ++r)
                        XI(xt, tt * 16 + q * 4 + r, n2 + nt * 16 + l15) += acc[nt][r] + bias2[nt];
            }
        }
        __syncthreads();                       // P5: x updated, U reads done
    }

    // ================= store: coalesced f32x4, swizzle-aware ===============
    #pragma unroll
    for (int xt = 0; xt < 4; ++xt) {
        float* xo = xout + (size_t)(blockIdx.x * 128 + xt * 32) * HD;
        #pragma unroll
        for (int j = 0; j < 2; ++j) {
            const int idx = j * 512 + t;       // f32x4 index within 32x128 tile
            const int r2  = idx >> 5;
            const int c4  = (idx & 31) * 4;
            *(f32x4*)(xo + (size_t)idx * 4) = *(const f32x4*)&XI(xt, r2, c4);
        }
    }
}

// ---------------------------------------------------------------------------
extern "C" void kernel_launch(void* const* d_in, const int* in_sizes, int n_in,
                              void* d_out, int out_size, void* d_ws, size_t ws_size,
                              hipStream_t stream)
{
    (void)in_sizes; (void)n_in; (void)out_size; (void)ws_size;

    const void* bt  = d_in[0];   // (B,NB,H)
    const void* es  = d_in[1];   // (E,)
    const void* ctE = d_in[2];   // (NCT,E)
    const void* Wp  = d_in[3];   // (H,H)
    const void* bp  = d_in[4];   // (H,)
    const void* Wg  = d_in[5];   // (2H,H)
    const void* bg  = d_in[6];   // (H,)
    const void* lns = d_in[7];   // (NL,H)
    const void* lnb = d_in[8];   // (NL,H)
    const void* W1  = d_in[9];   // (NL,H,2H)
    const void* b1  = d_in[10];  // (NL,2H)
    const void* W2  = d_in[11];  // (NL,2H,H)
    const void* b2  = d_in[12];  // (NL,H)
    const int* ctype = (const int*)d_in[13];
    const int* esrc  = (const int*)d_in[14];
    const int* edst  = (const int*)d_in[15];
    const void* act  = d_in[16]; // (B,NB)

    // Outputs f32, concatenated: x (M*HD) then edge_w (B*E). x lives in d_out.
    float* out_x  = (float*)d_out;
    float* out_ew = out_x + (size_t)MTOT * HD;
    float* x = out_x;

    // Workspace:
    //   [0,1K)              flags
    //   [1K,+16MB)          msg bf16
    //   [1K+16MB,+32MB)     bt16 bf16
    //   [1K+32MB,+48MB)     hr bf16
    //   base48 = 1K+48MB:
    //     cnt @+0 (16K) | ofs @+16K (20K) | cur @+36K (16K)
    //     eidx @+52K (256K) | pos_e @+308K (256K) | WT @+576K (352K)
    //     compact @+1M (8MB)
    char* ws = (char*)d_ws;
    int*            flags = (int*)ws;
    unsigned short* msg   = (unsigned short*)(ws + 1024);
    unsigned short* bt16  = (unsigned short*)(ws + 1024 + (16ull << 20));
    unsigned short* hr    = (unsigned short*)(ws + 1024 + (32ull << 20));
    char* base48 = ws + 1024 + (48ull << 20);
    int*            cnt     = (int*)(base48);
    int*            ofs     = (int*)(base48 + (16 << 10));
    int*            cur     = (int*)(base48 + (36 << 10));
    int*            eidx    = (int*)(base48 + (52 << 10));
    int*            pos_e   = (int*)(base48 + (308 << 10));
    unsigned short* WT      = (unsigned short*)(base48 + (576 << 10));
    float2*         compact = (float2*)(base48 + (1 << 20));

    const int M = MTOT;

    probe_k<<<1, 64, 0, stream>>>((const unsigned int*)es, (const unsigned int*)act, flags);
    hipMemsetAsync(cnt, 0, NBLK * sizeof(int), stream);

    transpose_k<<<dim3(128, 6), 256, 0, stream>>>(Wp, Wg, W1, W1, W2, W2, WT, flags);

    // fused cvt + route GEMM: bt -> bt16, hr = elu(bt @ Wp + bp)
    route_k<<<dim3(M / 128), 256, 0, stream>>>(bt, bt16, WT + 0, bp, hr, flags);

    csr_count_k<<<dim3(NE / 256), 256, 0, stream>>>(edst, cnt);
    csr_scan_k<<<dim3(1), 1024, 0, stream>>>(cnt, ofs, cur);
    csr_fill_k<<<dim3(NE / 256), 256, 0, stream>>>(edst, cur, eidx, pos_e);

    edge_k<<<dim3((BB * NE) / 256), 256, 0, stream>>>(
        es, ctE, ctype, esrc, edst, act, pos_e, out_ew, compact, flags);

    // messages via dst-centric segmented reduction -> bf16
    gather_k<<<dim3(M / 4), 256, 0, stream>>>(compact, ofs, hr, msg);

    // gate + both transformer layers fused; 128 rows/block, 8 waves, grid 512
    mega_k<<<dim3(M / 128), 512, 0, stream>>>(
        bt16, msg, bt, WT, bg, b1, b2, lns, lnb, x, flags);
}